// Round 3
// baseline (110.995 us; speedup 1.0000x reference)
//
#include <hip/hip_runtime.h>

// CharRNN GRU: B=4096, T=256, V=256, H=20, L=15, reset_after=True, drop_rate=0.
// All tensors f32 (proven: bf16-layout read -> NaN; f32 read -> sane).
// Output f32. 20 threads per batch element; recurrent math fp32 in registers.
// xW gather table in LDS: z/r gates bf16 (error-attenuated), h-gate f32.

#define BB 4096
#define TT 256
#define VV 256
#define HH 20
#define G3 60   // 3*H
#define LL 15
#define NB 8                 // batch elements per block
#define NTHREADS (NB * HH)   // 160

__device__ __forceinline__ float bf2f(unsigned short u) {
    union { unsigned int i; float f; } c;
    c.i = ((unsigned int)u) << 16;
    return c.f;
}

__device__ __forceinline__ unsigned short f2bf(float f) {
    union { float f; unsigned int i; } c;
    c.f = f;
    unsigned int x = c.i;
    return (unsigned short)((x + 0x7FFFu + ((x >> 16) & 1u)) >> 16); // RNE
}

__device__ __forceinline__ float fast_rcp(float x) {
#if __has_builtin(__builtin_amdgcn_rcpf)
    return __builtin_amdgcn_rcpf(x);
#else
    return 1.0f / x;
#endif
}

__device__ __forceinline__ float fast_sigmoid(float x) {
    return fast_rcp(1.0f + __expf(-x));
}

__device__ __forceinline__ float fast_tanh(float x) {
    return 1.0f - 2.0f * fast_rcp(1.0f + __expf(2.0f * x));
}

__global__ __launch_bounds__(NTHREADS) void gru_kernel(
    const int* __restrict__ x,            // [B][T] int32
    const float* __restrict__ kernelW,    // [V][3H] f32
    const float* __restrict__ rkernel,    // [H][3H] f32
    const float* __restrict__ bias,       // [2][3H] f32
    const float* __restrict__ dense_w,    // [H][L] f32
    const float* __restrict__ dense_b,    // [L] f32
    float* __restrict__ out)              // [B][L] f32
{
    __shared__ unsigned short xwzr_lds[VV * 2 * HH]; // z,r parts bf16 (20480 B)
    __shared__ float xwh_lds[VV * HH];               // h part f32    (20480 B)
    __shared__ float u_lds[HH * G3];                 // recurrent kernel f32
    __shared__ float w_lds[HH * LL];                 // dense W f32
    __shared__ float db_lds[LL];
    __shared__ int   x_lds[NB * (TT + 1)];           // +1 pad vs stride-256 banks
    __shared__ float hbuf[2][NB * HH];               // double-buffered hidden state

    const int tid = threadIdx.x;
    const int b0 = blockIdx.x * NB;

    // ---- staging ----
    for (int idx = tid; idx < VV * G3; idx += NTHREADS) {
        const int row = idx / G3, col = idx - row * G3;
        const float v = kernelW[idx] + bias[col];    // fold input bias
        if (col < 2 * HH) xwzr_lds[row * 2 * HH + col] = f2bf(v);
        else              xwh_lds[row * HH + (col - 2 * HH)] = v;
    }
    for (int idx = tid; idx < HH * G3; idx += NTHREADS)
        u_lds[idx] = rkernel[idx];
    for (int idx = tid; idx < HH * LL; idx += NTHREADS)
        w_lds[idx] = dense_w[idx];
    if (tid < LL) db_lds[tid] = dense_b[tid];
    for (int k = tid; k < NB * TT; k += NTHREADS)
        x_lds[(k >> 8) * (TT + 1) + (k & 255)] = x[(size_t)b0 * TT + k];
    hbuf[0][tid] = 0.0f;   // NB*HH == NTHREADS exactly
    __syncthreads();

    const int g = tid / HH;        // local batch
    const int j = tid - g * HH;    // hidden/gate column

    // recurrent kernel columns j, H+j, 2H+j in registers (60 VGPRs)
    float Uz[HH], Ur[HH], Uh[HH];
    #pragma unroll
    for (int i = 0; i < HH; ++i) {
        Uz[i] = u_lds[i * G3 + j];
        Ur[i] = u_lds[i * G3 + HH + j];
        Uh[i] = u_lds[i * G3 + 2 * HH + j];
    }
    const float brz = bias[G3 + j];
    const float brr = bias[G3 + HH + j];
    const float brh = bias[G3 + 2 * HH + j];

    float hmine = 0.0f;
    const int* xrow = &x_lds[g * (TT + 1)];

    auto step = [&](int t, const float* hread, float* hwrite) {
        const int xv = xrow[t];
        const float xz = bf2f(xwzr_lds[xv * 2 * HH + j]);
        const float xr = bf2f(xwzr_lds[xv * 2 * HH + HH + j]);
        const float xh = xwh_lds[xv * HH + j];

        float hz = brz, hr = brr, hh = brh;  // accumulators start at recurrent bias
        const float4* h4 = (const float4*)(hread + g * HH);
        #pragma unroll
        for (int q = 0; q < HH / 4; ++q) {
            const float4 hv = h4[q];
            hz = fmaf(hv.x, Uz[4*q+0], hz); hr = fmaf(hv.x, Ur[4*q+0], hr); hh = fmaf(hv.x, Uh[4*q+0], hh);
            hz = fmaf(hv.y, Uz[4*q+1], hz); hr = fmaf(hv.y, Ur[4*q+1], hr); hh = fmaf(hv.y, Uh[4*q+1], hh);
            hz = fmaf(hv.z, Uz[4*q+2], hz); hr = fmaf(hv.z, Ur[4*q+2], hr); hh = fmaf(hv.z, Uh[4*q+2], hh);
            hz = fmaf(hv.w, Uz[4*q+3], hz); hr = fmaf(hv.w, Ur[4*q+3], hr); hh = fmaf(hv.w, Uh[4*q+3], hh);
        }
        const float z  = fast_sigmoid(xz + hz);
        const float r  = fast_sigmoid(xr + hr);
        const float hc = fast_tanh(fmaf(r, hh, xh));
        hmine = hc + z * (hmine - hc);
        hwrite[g * HH + j] = hmine;
        __syncthreads();
    };

    for (int t = 0; t < TT; t += 2) {
        step(t,     hbuf[0], hbuf[1]);
        step(t + 1, hbuf[1], hbuf[0]);
    }
    // T even -> final h lives in hbuf[0]

    // ---- dense head: logits[b][l] = db[l] + sum_i h[i] * W[i][l] ----
    if (j < LL) {
        float acc = db_lds[j];
        const float* hfin = &hbuf[0][g * HH];
        #pragma unroll
        for (int i = 0; i < HH; ++i)
            acc = fmaf(hfin[i], w_lds[i * LL + j], acc);
        out[(size_t)(b0 + g) * LL + j] = acc;
    }
}

extern "C" void kernel_launch(void* const* d_in, const int* in_sizes, int n_in,
                              void* d_out, int out_size, void* d_ws, size_t ws_size,
                              hipStream_t stream) {
    const int* x            = (const int*)d_in[0];
    // d_in[1] = drop_rate (0.0f) -> dropout is identity; ignored.
    const float* kernelW    = (const float*)d_in[2];
    const float* rkernel    = (const float*)d_in[3];
    const float* bias       = (const float*)d_in[4];
    const float* dense_w    = (const float*)d_in[5];
    const float* dense_b    = (const float*)d_in[6];
    float* out              = (float*)d_out;

    dim3 grid(BB / NB);      // 512 blocks
    dim3 block(NTHREADS);    // 160 threads (8 batches x 20)
    gru_kernel<<<grid, block, 0, stream>>>(x, kernelW, rkernel, bias,
                                           dense_w, dense_b, out);
}

// Round 4
// 96.551 us; speedup vs baseline: 1.1496x; 1.1496x over previous
//
#include <hip/hip_runtime.h>

// CharRNN GRU: B=4096, T=256, V=256, H=20, L=15, reset_after=True, drop_rate=0.
// f32 in / f32 out. Wave-local batches: lanes {0-19,20-39,40-59} of each wave
// own 3 batches; NO __syncthreads in the time loop. h exchange via LDS using
// the per-wave in-order DS pipeline + compiler memory fences.
// xW gather table: z/r packed bf16 (error-attenuated through sigmoid), h f32.

#define BB 4096
#define TT 256
#define VV 256
#define HH 20
#define G3 60    // 3*H
#define LL 15
#define NBATCH 12             // batches per block (4 waves x 3)
#define NTHREADS 256

__device__ __forceinline__ unsigned short f2bf(float f) {
    union { float f; unsigned int i; } c;
    c.f = f;
    unsigned int x = c.i;
    return (unsigned short)((x + 0x7FFFu + ((x >> 16) & 1u)) >> 16); // RNE
}

__device__ __forceinline__ float fast_rcp(float x) {
#if __has_builtin(__builtin_amdgcn_rcpf)
    return __builtin_amdgcn_rcpf(x);
#else
    return 1.0f / x;
#endif
}

__device__ __forceinline__ float fast_sigmoid(float x) {
    return fast_rcp(1.0f + __expf(-x));   // exp(-x): neg folds into src modifier
}

__device__ __forceinline__ float fast_tanh(float x) {
    return 1.0f - 2.0f * fast_rcp(1.0f + __expf(2.0f * x));
}

__global__ __launch_bounds__(NTHREADS) void gru_kernel(
    const int* __restrict__ x,            // [B][T] int32
    const float* __restrict__ kernelW,    // [V][3H] f32
    const float* __restrict__ rkernel,    // [H][3H] f32
    const float* __restrict__ bias,       // [2][3H] f32
    const float* __restrict__ dense_w,    // [H][L] f32
    const float* __restrict__ dense_b,    // [L] f32
    float* __restrict__ out)              // [B][L] f32
{
    __shared__ unsigned int xwzr[VV * HH];       // packed (z lo16, r hi16) bf16
    __shared__ float        xwh [VV * HH];       // h-gate part f32
    __shared__ float        u_lds[HH * G3];      // recurrent kernel f32
    __shared__ float        w_lds[HH * LL];      // dense W
    __shared__ float        db_lds[LL];
    __shared__ int          x_lds[NBATCH][TT + 1];   // +1 pad
    __shared__ float        hbuf[NBATCH * HH + 16];  // +16 scratch for idle lanes

    const int tid = threadIdx.x;
    const long b0 = (long)blockIdx.x * NBATCH;

    // ---- staging (block-wide, one barrier total) ----
    for (int idx = tid; idx < VV * HH; idx += NTHREADS) {
        const int v = idx / HH, j = idx - v * HH;
        const float vz = kernelW[v * G3 + j]          + bias[j];
        const float vr = kernelW[v * G3 + HH + j]     + bias[HH + j];
        xwzr[idx] = (unsigned int)f2bf(vz) | ((unsigned int)f2bf(vr) << 16);
        xwh[idx]  = kernelW[v * G3 + 2 * HH + j] + bias[2 * HH + j];
    }
    for (int idx = tid; idx < HH * G3; idx += NTHREADS) u_lds[idx] = rkernel[idx];
    for (int idx = tid; idx < HH * LL; idx += NTHREADS) w_lds[idx] = dense_w[idx];
    if (tid < LL) db_lds[tid] = dense_b[tid];
    for (int k = tid; k < NBATCH * TT; k += NTHREADS) {
        const long gi = b0 * TT + k;
        x_lds[k >> 8][k & 255] = (gi < (long)BB * TT) ? x[gi] : 0;
    }
    for (int idx = tid; idx < NBATCH * HH + 16; idx += NTHREADS) hbuf[idx] = 0.0f;
    __syncthreads();   // the ONLY block barrier

    const int lane = tid & 63;
    const int wv   = tid >> 6;
    const int g3   = lane / 20;            // 0..2 active, 3 for idle lanes
    const int j    = lane - g3 * 20;
    const bool active = (lane < 60);
    const int lb   = wv * 3 + g3;          // local batch (12.. for idle lanes)
    const int lbc  = active ? lb : 0;      // clamped for reads
    // idle lanes write to scratch past the real h region
    const int hwidx = active ? (lb * HH + j) : (NBATCH * HH + wv * 4 + (lane - 60));

    // recurrent kernel columns j, H+j, 2H+j in registers (60 VGPRs)
    float Uz[HH], Ur[HH], Uh[HH];
    #pragma unroll
    for (int i = 0; i < HH; ++i) {
        Uz[i] = u_lds[i * G3 + j];
        Ur[i] = u_lds[i * G3 + HH + j];
        Uh[i] = u_lds[i * G3 + 2 * HH + j];
    }
    const float brz = bias[G3 + j];
    const float brr = bias[G3 + HH + j];
    const float brh = bias[G3 + 2 * HH + j];

    float hmine = 0.0f;
    const float4* h4   = (const float4*)(hbuf + lbc * HH);  // 80B base: f4-aligned
    const int*    xrow = x_lds[lbc];

    for (int t = 0; t < TT; ++t) {
        // fence: previous iteration's ds_write ordered before these reads
        // (HW guarantees per-wave in-order DS execution; this stops the
        //  compiler from reordering/caching LDS accesses)
        asm volatile("" ::: "memory");
        const int xv = xrow[t];                      // wave: 3 addrs, broadcast
        const unsigned int zr = xwzr[xv * HH + j];
        const float xh = xwh[xv * HH + j];
        const float xz = __uint_as_float(zr << 16);
        const float xr = __uint_as_float(zr & 0xffff0000u);

        const float4 h0 = h4[0], h1 = h4[1], h2 = h4[2], h3 = h4[3], hv4 = h4[4];

        // two chains per gate: latency ~50cy instead of 80
        float za = brz, ra = brr, ha = brh;
        float zb = 0.f, rb = 0.f, hb = 0.f;
        za = fmaf(h0.x, Uz[0],  za); ra = fmaf(h0.x, Ur[0],  ra); ha = fmaf(h0.x, Uh[0],  ha);
        za = fmaf(h0.y, Uz[1],  za); ra = fmaf(h0.y, Ur[1],  ra); ha = fmaf(h0.y, Uh[1],  ha);
        za = fmaf(h0.z, Uz[2],  za); ra = fmaf(h0.z, Ur[2],  ra); ha = fmaf(h0.z, Uh[2],  ha);
        za = fmaf(h0.w, Uz[3],  za); ra = fmaf(h0.w, Ur[3],  ra); ha = fmaf(h0.w, Uh[3],  ha);
        za = fmaf(h1.x, Uz[4],  za); ra = fmaf(h1.x, Ur[4],  ra); ha = fmaf(h1.x, Uh[4],  ha);
        za = fmaf(h1.y, Uz[5],  za); ra = fmaf(h1.y, Ur[5],  ra); ha = fmaf(h1.y, Uh[5],  ha);
        za = fmaf(h1.z, Uz[6],  za); ra = fmaf(h1.z, Ur[6],  ra); ha = fmaf(h1.z, Uh[6],  ha);
        za = fmaf(h1.w, Uz[7],  za); ra = fmaf(h1.w, Ur[7],  ra); ha = fmaf(h1.w, Uh[7],  ha);
        zb = fmaf(h2.x, Uz[8],  zb); rb = fmaf(h2.x, Ur[8],  rb); hb = fmaf(h2.x, Uh[8],  hb);
        zb = fmaf(h2.y, Uz[9],  zb); rb = fmaf(h2.y, Ur[9],  rb); hb = fmaf(h2.y, Uh[9],  hb);
        zb = fmaf(h2.z, Uz[10], zb); rb = fmaf(h2.z, Ur[10], rb); hb = fmaf(h2.z, Uh[10], hb);
        zb = fmaf(h2.w, Uz[11], zb); rb = fmaf(h2.w, Ur[11], rb); hb = fmaf(h2.w, Uh[11], hb);
        zb = fmaf(h3.x, Uz[12], zb); rb = fmaf(h3.x, Ur[12], rb); hb = fmaf(h3.x, Uh[12], hb);
        zb = fmaf(h3.y, Uz[13], zb); rb = fmaf(h3.y, Ur[13], rb); hb = fmaf(h3.y, Uh[13], hb);
        zb = fmaf(h3.z, Uz[14], zb); rb = fmaf(h3.z, Ur[14], rb); hb = fmaf(h3.z, Uh[14], hb);
        zb = fmaf(h3.w, Uz[15], zb); rb = fmaf(h3.w, Ur[15], rb); hb = fmaf(h3.w, Uh[15], hb);
        zb = fmaf(hv4.x, Uz[16], zb); rb = fmaf(hv4.x, Ur[16], rb); hb = fmaf(hv4.x, Uh[16], hb);
        zb = fmaf(hv4.y, Uz[17], zb); rb = fmaf(hv4.y, Ur[17], rb); hb = fmaf(hv4.y, Uh[17], hb);
        zb = fmaf(hv4.z, Uz[18], zb); rb = fmaf(hv4.z, Ur[18], rb); hb = fmaf(hv4.z, Uh[18], hb);
        zb = fmaf(hv4.w, Uz[19], zb); rb = fmaf(hv4.w, Ur[19], rb); hb = fmaf(hv4.w, Uh[19], hb);

        const float z  = fast_sigmoid(xz + (za + zb));
        const float r  = fast_sigmoid(xr + (ra + rb));
        const float hc = fast_tanh(fmaf(r, ha + hb, xh));
        hmine = hc + z * (hmine - hc);

        // fence: reads above ordered before this write (WAR within wave)
        asm volatile("" ::: "memory");
        hbuf[hwidx] = hmine;
    }

    asm volatile("" ::: "memory");

    // ---- dense head: logits[b][l] = db[l] + sum_i h[i] * W[i][l] ----
    const long gb = b0 + lb;
    if (active && j < LL && gb < BB) {
        float acc = db_lds[j];
        const float* hfin = &hbuf[lb * HH];
        #pragma unroll
        for (int i = 0; i < HH; ++i)
            acc = fmaf(hfin[i], w_lds[i * LL + j], acc);
        out[gb * LL + j] = acc;
    }
}

extern "C" void kernel_launch(void* const* d_in, const int* in_sizes, int n_in,
                              void* d_out, int out_size, void* d_ws, size_t ws_size,
                              hipStream_t stream) {
    const int* x            = (const int*)d_in[0];
    // d_in[1] = drop_rate (0.0f) -> dropout is identity; ignored.
    const float* kernelW    = (const float*)d_in[2];
    const float* rkernel    = (const float*)d_in[3];
    const float* bias       = (const float*)d_in[4];
    const float* dense_w    = (const float*)d_in[5];
    const float* dense_b    = (const float*)d_in[6];
    float* out              = (float*)d_out;

    dim3 grid((BB + NBATCH - 1) / NBATCH);   // 342 blocks
    dim3 block(NTHREADS);                    // 256 threads = 4 waves = 12 batches
    gru_kernel<<<grid, block, 0, stream>>>(x, kernelW, rkernel, bias,
                                           dense_w, dense_b, out);
}